// Round 2
// baseline (1432.677 us; speedup 1.0000x reference)
//
#include <hip/hip_runtime.h>
#include <stdint.h>

// ---------------------------------------------------------------------------
// MoE top-2 FFN on gfx950: fp32 gating (exact expert selection), fp16 MFMA
// grouped GEMMs (m97-style: 128x128 tile, BK=64, global_load_lds width=16,
// XOR-swizzled LDS, ds_read_b128 frags), atomic fp32 scatter-combine epilogue.
// Workspace-adaptive: fast path stages converted w1/w3 in d_out (64 MB exact),
// fallback slices F into S passes to shrink hbuf.
// ---------------------------------------------------------------------------

typedef _Float16 f16;
typedef f16  f16x8 __attribute__((ext_vector_type(8)));
typedef f16  f16x4 __attribute__((ext_vector_type(4)));
typedef float fx4  __attribute__((ext_vector_type(4)));

#define NEXP 8
// meta layout (ints): [0..7] counts, [8..15] cursors, [16..24] expert_off,
// [32..543] tile_expert, [544..1055] tile_row0.  memset 8 KiB each launch.
#define M_CNT  0
#define M_CUR  8
#define M_OFF  16
#define M_TE   32
#define M_TR   544

__device__ __forceinline__ void gload_lds16(const f16* g, f16* l) {
  // global->LDS DMA, 16 B/lane. LDS dest is wave-uniform base + lane*16.
  __builtin_amdgcn_global_load_lds(
      (const __attribute__((address_space(1))) void*)g,
      (__attribute__((address_space(3))) void*)l, 16, 0, 0);
}

// ---------------- w1/w3 -> interleaved fp16 slice  [E][2*FS][D] -------------
// row rr even -> w1[e][fbase + rr/2], odd -> w3[e][fbase + rr/2]
__global__ __launch_bounds__(256) void cvt_w13_kernel(const float* __restrict__ w1,
                                                      const float* __restrict__ w3,
                                                      f16* __restrict__ w13,
                                                      int D, int F, int FS, int fbase) {
  long i = (long)blockIdx.x * 256 + threadIdx.x;          // float4 id
  long n4 = (long)NEXP * 2 * FS * (D / 4);
  if (i >= n4) return;
  int d4 = (int)(i % (D / 4));
  int rr = (int)((i / (D / 4)) % (2 * FS));
  int e  = (int)(i / ((long)(D / 4) * 2 * FS));
  const float* src = ((rr & 1) ? w3 : w1) + ((long)e * F + fbase + (rr >> 1)) * D + d4 * 4;
  float4 v = *(const float4*)src;
  f16x4 o = {(f16)v.x, (f16)v.y, (f16)v.z, (f16)v.w};
  *(f16x4*)(w13 + i * 4) = o;
}

// ---------------- w2 -> fp16 k-slice  [E][D][FS] ---------------------------
__global__ __launch_bounds__(256) void cvt_w2_kernel(const float* __restrict__ w2,
                                                     f16* __restrict__ w2s,
                                                     int D, int F, int FS, int fbase) {
  long i = (long)blockIdx.x * 256 + threadIdx.x;          // float4 id
  long n4 = (long)NEXP * D * (FS / 4);
  if (i >= n4) return;
  int k4 = (int)(i % (FS / 4));
  int d  = (int)((i / (FS / 4)) % D);
  int e  = (int)(i / ((long)(FS / 4) * D));
  const float* src = w2 + ((long)e * D + d) * F + fbase + k4 * 4;
  float4 v = *(const float4*)src;
  f16x4 o = {(f16)v.x, (f16)v.y, (f16)v.z, (f16)v.w};
  *(f16x4*)(w2s + i * 4) = o;
}

// ---------------- gating: fp32 logits, top-2, x->fp16 ----------------
__global__ __launch_bounds__(256) void gate_kernel(const float* __restrict__ x,
                                                   const float* __restrict__ gw,
                                                   f16* __restrict__ xb,
                                                   int* __restrict__ meta,
                                                   int* __restrict__ topk_id,
                                                   float* __restrict__ topk_w,
                                                   int D) {
  const int lane = threadIdx.x & 63;
  const int wave = threadIdx.x >> 6;
  const long tok = (long)blockIdx.x * 4 + wave;
  const float* xrow = x + tok * D;

  float part[NEXP];
#pragma unroll
  for (int e = 0; e < NEXP; ++e) part[e] = 0.f;

  for (int c = 0; c < D / 256; ++c) {
    int idx = (c * 64 + lane) * 4;
    float4 xv = *(const float4*)(xrow + idx);
    f16x4 o = {(f16)xv.x, (f16)xv.y, (f16)xv.z, (f16)xv.w};
    *(f16x4*)(xb + tok * D + idx) = o;
#pragma unroll
    for (int e = 0; e < NEXP; ++e) {
      float4 gv = *(const float4*)(gw + (long)e * D + idx);
      part[e] += xv.x * gv.x + xv.y * gv.y + xv.z * gv.z + xv.w * gv.w;
    }
  }
#pragma unroll
  for (int e = 0; e < NEXP; ++e)
    for (int off = 32; off; off >>= 1) part[e] += __shfl_xor(part[e], off);

  // top-2, lowest index wins ties (matches lax.top_k stable ordering)
  int i0 = 0; float m0 = part[0];
#pragma unroll
  for (int e = 1; e < NEXP; ++e) if (part[e] > m0) { m0 = part[e]; i0 = e; }
  int i1 = (i0 == 0) ? 1 : 0; float m1 = part[i1];
#pragma unroll
  for (int e = 0; e < NEXP; ++e)
    if (e != i0 && e != ((i0 == 0) ? 1 : 0) && part[e] > m1) { m1 = part[e]; i1 = e; }

  if (lane == 0) {
    // renormalized top-2 softmax == sigmoid of logit difference
    float w0 = 1.f / (1.f + expf(m1 - m0));
    float w1 = 1.f / (1.f + expf(m0 - m1));
    topk_id[2 * tok] = i0; topk_id[2 * tok + 1] = i1;
    topk_w[2 * tok] = w0;  topk_w[2 * tok + 1] = w1;
    atomicAdd(meta + M_CNT + i0, 1);
    atomicAdd(meta + M_CNT + i1, 1);
  }
}

// ---------------- offsets + tile map + pad fill ----------------
__global__ void setup_kernel(int* __restrict__ meta, int* __restrict__ routed_token,
                             float* __restrict__ routed_w, int MT) {
  __shared__ int s_off[NEXP], s_cnt[NEXP];
  const int t = threadIdx.x;
  if (t == 0) {
    int off = 0, tt = 0;
    for (int e = 0; e < NEXP; ++e) {
      int c = meta[M_CNT + e];
      s_cnt[e] = c; s_off[e] = off;
      meta[M_OFF + e] = off;
      int p = (c + 127) & ~127;
      for (int i = 0; i < (p >> 7); ++i) {
        meta[M_TE + tt] = e; meta[M_TR + tt] = off + i * 128; ++tt;
      }
      off += p;
    }
    meta[M_OFF + NEXP] = off;
    for (; tt < MT; ++tt) meta[M_TE + tt] = -1;
  }
  __syncthreads();
  for (int e = 0; e < NEXP; ++e) {
    int start = s_off[e] + s_cnt[e];
    int end = s_off[e] + ((s_cnt[e] + 127) & ~127);
    for (int i = start + t; i < end; i += blockDim.x) {
      routed_token[i] = 0;      // pad rows -> token 0 (finite garbage)
      routed_w[i] = 0.f;        // zero gate weight kills pad contribution
    }
  }
}

// ---------------- scatter tokens into per-expert slots ----------------
__global__ __launch_bounds__(256) void scatter_kernel(const int* __restrict__ topk_id,
                                                      const float* __restrict__ topk_w,
                                                      int* __restrict__ meta,
                                                      int* __restrict__ routed_token,
                                                      float* __restrict__ routed_w,
                                                      int n2) {
  int tid = blockIdx.x * 256 + threadIdx.x;
  if (tid >= n2) return;
  int e = topk_id[tid];
  int pos = atomicAdd(meta + M_CUR + e, 1);
  int slot = meta[M_OFF + e] + pos;
  routed_token[slot] = tid >> 1;
  routed_w[slot] = topk_w[tid];
}

// ---------------- GEMM1: h = silu(X w1^T) * (X w3^T), fused dual-B ----------
// Tile: 128 token-rows x 128 interleaved weight-rows (2j=w1[f0+j], 2j+1=w3).
// Waves 2x2 (64x64 each). BK=64, 2 MFMA K-steps per chunk.
__global__ __launch_bounds__(256) void ffn1_kernel(const f16* __restrict__ xb,
                                                   const f16* __restrict__ w13,
                                                   const int* __restrict__ routed_token,
                                                   const int* __restrict__ meta,
                                                   f16* __restrict__ hbuf,
                                                   int D, int FS) {
  const int e = meta[M_TE + blockIdx.x];
  if (e < 0) return;
  const int r0 = meta[M_TR + blockIdx.x];
  const int f0 = blockIdx.y * 64;          // local to this F-slice

  __shared__ __align__(16) f16 smem[2 * 128 * 64];  // 32 KiB: sA | sB; epilogue reuses
  f16* sA = smem;
  f16* sB = smem + 128 * 64;

  const int t = threadIdx.x;
  const int lane = t & 63;
  const int wave = t >> 6;
  const int wm = (wave & 1) * 64;
  const int wn = (wave >> 1) * 64;

  // staging: thread t owns granule gi=q*256+t -> row q*32+(t>>3), col-gran t&7.
  // XOR swizzle on the GLOBAL side: LDS (r,g) holds global (r, g^(r&7)).
  const int rb = t >> 3;
  const int sgg = (t & 7) ^ (rb & 7);
  const f16* aptr[4];
  const f16* bptr[4];
#pragma unroll
  for (int q = 0; q < 4; ++q) {
    int r = q * 32 + rb;
    int tok = routed_token[r0 + r];
    aptr[q] = xb + (long)tok * D + sgg * 8;
    bptr[q] = w13 + ((long)e * 2 * FS + 2 * f0 + r) * D + sgg * 8;
  }
  f16* ldsA[4]; f16* ldsB[4];
#pragma unroll
  for (int q = 0; q < 4; ++q) {
    int gbase = (q * 256 + (t & ~63)) * 8;   // wave-uniform
    ldsA[q] = sA + gbase;
    ldsB[q] = sB + gbase;
  }

  fx4 acc[4][4];
#pragma unroll
  for (int i = 0; i < 4; ++i)
#pragma unroll
    for (int j = 0; j < 4; ++j) acc[i][j] = (fx4){0.f, 0.f, 0.f, 0.f};

  for (int kc = 0; kc < D; kc += 64) {
#pragma unroll
    for (int q = 0; q < 4; ++q) {
      gload_lds16(aptr[q] + kc, ldsA[q]);
      gload_lds16(bptr[q] + kc, ldsB[q]);
    }
    __syncthreads();
#pragma unroll
    for (int ks = 0; ks < 2; ++ks) {
      f16x8 aF[4], bF[4];
      const int kg = ks * 4 + (lane >> 4);
#pragma unroll
      for (int mf = 0; mf < 4; ++mf) {
        int row = wm + mf * 16 + (lane & 15);
        aF[mf] = *(const f16x8*)(sA + row * 64 + (kg ^ (row & 7)) * 8);
      }
#pragma unroll
      for (int nf = 0; nf < 4; ++nf) {
        int row = wn + nf * 16 + (lane & 15);
        bF[nf] = *(const f16x8*)(sB + row * 64 + (kg ^ (row & 7)) * 8);
      }
#pragma unroll
      for (int mf = 0; mf < 4; ++mf)
#pragma unroll
        for (int nf = 0; nf < 4; ++nf)
          acc[mf][nf] = __builtin_amdgcn_mfma_f32_16x16x32_f16(aF[mf], bF[nf], acc[mf][nf], 0, 0, 0);
    }
    __syncthreads();
  }

  // epilogue: pair even(w1)/odd(w3) cols, silu*mul, repack via LDS, wide stores
  f16* sH = smem;                       // [128][72] padded (+8 kills write conflicts)
#pragma unroll
  for (int mf = 0; mf < 4; ++mf)
#pragma unroll
    for (int nf = 0; nf < 4; ++nf)
#pragma unroll
      for (int rg = 0; rg < 4; ++rg) {
        float v = acc[mf][nf][rg];
        float pv = __shfl_xor(v, 1);
        float c1 = (lane & 1) ? pv : v;
        float c3 = (lane & 1) ? v : pv;
        float hv = c1 / (1.f + expf(-c1)) * c3;
        int ml = wm + mf * 16 + (lane >> 4) * 4 + rg;
        int fl = (wn + nf * 16 + (lane & 15)) >> 1;
        sH[ml * 72 + fl] = (f16)hv;     // both lanes of a pair write same value
      }
  __syncthreads();
#pragma unroll
  for (int q = 0; q < 4; ++q) {
    int gi = q * 256 + t;
    int r = gi >> 3, gc = gi & 7;
    *(f16x8*)(hbuf + (long)(r0 + r) * FS + f0 + gc * 8) = *(const f16x8*)(sH + r * 72 + gc * 8);
  }
}

// ---------------- GEMM2: out[tok] += gate_w * (h @ w2^T) slice --------------
__global__ __launch_bounds__(256) void ffn2_kernel(const f16* __restrict__ hbuf,
                                                   const f16* __restrict__ w2s,
                                                   const int* __restrict__ routed_token,
                                                   const float* __restrict__ routed_w,
                                                   const int* __restrict__ meta,
                                                   float* __restrict__ out,
                                                   int D, int FS) {
  const int e = meta[M_TE + blockIdx.x];
  if (e < 0) return;
  const int r0 = meta[M_TR + blockIdx.x];
  const int d0 = blockIdx.y * 128;

  __shared__ __align__(16) f16 smem[2 * 128 * 64];   // 32 KiB staging
  __shared__ int   s_tok[128];
  __shared__ float s_w[128];
  f16* sA = smem;
  f16* sB = smem + 128 * 64;

  const int t = threadIdx.x;
  const int lane = t & 63;
  const int wave = t >> 6;
  const int wm = (wave & 1) * 64;
  const int wn = (wave >> 1) * 64;

  if (t < 128) {
    s_tok[t] = routed_token[r0 + t];
    s_w[t] = routed_w[r0 + t];
  }

  const int rb = t >> 3;
  const int sgg = (t & 7) ^ (rb & 7);
  const f16* aptr[4];
  const f16* bptr[4];
#pragma unroll
  for (int q = 0; q < 4; ++q) {
    int r = q * 32 + rb;
    aptr[q] = hbuf + (long)(r0 + r) * FS + sgg * 8;
    bptr[q] = w2s + ((long)e * D + d0 + r) * FS + sgg * 8;
  }
  f16* ldsA[4]; f16* ldsB[4];
#pragma unroll
  for (int q = 0; q < 4; ++q) {
    int gbase = (q * 256 + (t & ~63)) * 8;
    ldsA[q] = sA + gbase;
    ldsB[q] = sB + gbase;
  }

  fx4 acc[4][4];
#pragma unroll
  for (int i = 0; i < 4; ++i)
#pragma unroll
    for (int j = 0; j < 4; ++j) acc[i][j] = (fx4){0.f, 0.f, 0.f, 0.f};

  for (int kc = 0; kc < FS; kc += 64) {
#pragma unroll
    for (int q = 0; q < 4; ++q) {
      gload_lds16(aptr[q] + kc, ldsA[q]);
      gload_lds16(bptr[q] + kc, ldsB[q]);
    }
    __syncthreads();
#pragma unroll
    for (int ks = 0; ks < 2; ++ks) {
      f16x8 aF[4], bF[4];
      const int kg = ks * 4 + (lane >> 4);
#pragma unroll
      for (int mf = 0; mf < 4; ++mf) {
        int row = wm + mf * 16 + (lane & 15);
        aF[mf] = *(const f16x8*)(sA + row * 64 + (kg ^ (row & 7)) * 8);
      }
#pragma unroll
      for (int nf = 0; nf < 4; ++nf) {
        int row = wn + nf * 16 + (lane & 15);
        bF[nf] = *(const f16x8*)(sB + row * 64 + (kg ^ (row & 7)) * 8);
      }
#pragma unroll
      for (int mf = 0; mf < 4; ++mf)
#pragma unroll
        for (int nf = 0; nf < 4; ++nf)
          acc[mf][nf] = __builtin_amdgcn_mfma_f32_16x16x32_f16(aF[mf], bF[nf], acc[mf][nf], 0, 0, 0);
    }
    __syncthreads();
  }

  // epilogue: out[tok, d0+nl] += gate_w * acc   (2 disjoint adds per element)
#pragma unroll
  for (int mf = 0; mf < 4; ++mf) {
#pragma unroll
    for (int rg = 0; rg < 4; ++rg) {
      int row = wm + mf * 16 + (lane >> 4) * 4 + rg;
      float w = s_w[row];
      long obase = (long)s_tok[row] * D + d0;
      if (w != 0.f) {
#pragma unroll
        for (int nf = 0; nf < 4; ++nf) {
          int nl = wn + nf * 16 + (lane & 15);
          atomicAdd(out + obase + nl, w * acc[mf][nf][rg]);
        }
      }
    }
  }
}

// ---------------------------------------------------------------------------
extern "C" void kernel_launch(void* const* d_in, const int* in_sizes, int n_in,
                              void* d_out, int out_size, void* d_ws, size_t ws_size,
                              hipStream_t stream) {
  const float* x  = (const float*)d_in[0];
  const float* gw = (const float*)d_in[1];
  const float* w1 = (const float*)d_in[2];
  const float* w2 = (const float*)d_in[3];
  const float* w3 = (const float*)d_in[4];
  float* out = (float*)d_out;

  const int E = NEXP;
  const int D = in_sizes[1] / E;                              // 1024
  const long N = (long)in_sizes[0] / D;                       // 16384
  const int F = (int)((long)in_sizes[2] / ((long)E * D));     // 2048
  const int MT = (int)(2 * N / 128 + E);                      // 264 m-tiles max
  const long RMAX = (long)MT * 128;
  const long out_bytes = (long)out_size * 4;

  char* base = (char*)d_ws;
  long off = 0;
  int*   meta         = (int*)(base + off); off += 8 * 1024;
  int*   topk_id      = (int*)(base + off); off += 2 * N * 4;
  float* topk_w       = (float*)(base + off); off += 2 * N * 4;
  int*   routed_token = (int*)(base + off); off += RMAX * 4;
  float* routed_w     = (float*)(base + off); off += RMAX * 4;
  off = (off + 255) & ~255L;
  f16* xb = (f16*)(base + off); off += N * (long)D * 2;
  const long fixed = off;

  // choose slicing S so everything fits. Fast path: w13 lives in d_out (64MB).
  int S = 0; bool w13_in_dout = false;
  {
    long need1 = fixed + (long)E * D * F * 2 + RMAX * (long)F * 2;
    if (need1 <= (long)ws_size && out_bytes >= (long)E * 2 * F * D * 2) {
      S = 1; w13_in_dout = true;
    } else {
      const int cands[4] = {2, 4, 8, 16};
      for (int ci = 0; ci < 4 && !S; ++ci) {
        int s = cands[ci];
        if (F % (64 * s)) continue;
        long FSl = F / s;
        long need = fixed + (long)E * D * FSl * 2 + RMAX * FSl * 2 + (long)E * 2 * FSl * D * 2;
        if (need <= (long)ws_size) S = s;
      }
    }
  }
  if (!S) return;
  const int FS = F / S;
  f16* w2s = (f16*)(base + off); off += (long)E * D * FS * 2;
  f16* hbuf = (f16*)(base + off); off += RMAX * (long)FS * 2;
  f16* w13 = w13_in_dout ? (f16*)d_out : (f16*)(base + off);

  hipMemsetAsync(meta, 0, 8 * 1024, stream);
  gate_kernel<<<(int)(N / 4), 256, 0, stream>>>(x, gw, xb, meta, topk_id, topk_w, D);
  setup_kernel<<<1, 256, 0, stream>>>(meta, routed_token, routed_w, MT);
  scatter_kernel<<<(int)((2 * N + 255) / 256), 256, 0, stream>>>(
      topk_id, topk_w, meta, routed_token, routed_w, (int)(2 * N));

  const long n13 = (long)E * 2 * FS * (D / 4);
  const long nw2 = (long)E * D * (FS / 4);
  const int b13 = (int)((n13 + 255) / 256);
  const int bw2 = (int)((nw2 + 255) / 256);

  if (w13_in_dout) {
    cvt_w13_kernel<<<b13, 256, 0, stream>>>(w1, w3, w13, D, F, FS, 0);
    cvt_w2_kernel<<<bw2, 256, 0, stream>>>(w2, w2s, D, F, FS, 0);
    dim3 g1(MT, FS / 64);
    ffn1_kernel<<<g1, 256, 0, stream>>>(xb, w13, routed_token, meta, hbuf, D, FS);
    hipMemsetAsync(out, 0, out_bytes, stream);   // w13 (in d_out) dead now
    dim3 g2(MT, D / 128);
    ffn2_kernel<<<g2, 256, 0, stream>>>(hbuf, w2s, routed_token, routed_w, meta, out, D, FS);
  } else {
    hipMemsetAsync(out, 0, out_bytes, stream);
    for (int s = 0; s < S; ++s) {
      int fbase = s * FS;
      cvt_w13_kernel<<<b13, 256, 0, stream>>>(w1, w3, w13, D, F, FS, fbase);
      cvt_w2_kernel<<<bw2, 256, 0, stream>>>(w2, w2s, D, F, FS, fbase);
      dim3 g1(MT, FS / 64);
      ffn1_kernel<<<g1, 256, 0, stream>>>(xb, w13, routed_token, meta, hbuf, D, FS);
      dim3 g2(MT, D / 128);
      ffn2_kernel<<<g2, 256, 0, stream>>>(hbuf, w2s, routed_token, routed_w, meta, out, D, FS);
    }
  }
}

// Round 3
// 1083.565 us; speedup vs baseline: 1.3222x; 1.3222x over previous
//
#include <hip/hip_runtime.h>
#include <stdint.h>

// ---------------------------------------------------------------------------
// MoE top-2 FFN on gfx950: fp32 gating (exact expert selection), fp16 MFMA
// grouped GEMMs (m97-style: 128x128 tile, BK=64, global_load_lds width=16,
// XOR-swizzled LDS, ds_read_b128 frags), atomic fp32 scatter-combine epilogue.
// R2->R3: native __expf + dedup silu epilogue (was libm expf, 2x redundant);
// hierarchical routing (LDS histograms) replaces contended global atomics;
// gate weight folded into h rows.
// ---------------------------------------------------------------------------

typedef _Float16 f16;
typedef f16  f16x8 __attribute__((ext_vector_type(8)));
typedef f16  f16x4 __attribute__((ext_vector_type(4)));
typedef float fx4  __attribute__((ext_vector_type(4)));

#define NEXP 8
#define CHUNK 1024          // assignments per routing block
// meta layout (ints):
#define M_PART 0            // [32*8] per-block expert counts
#define M_OFF  256          // [9] expert slot offsets (padded 128)
#define M_BB   272          // [32*8] per-block scatter bases
#define M_TE   528          // [<=512] tile -> expert
#define M_TR   1040         // [<=512] tile -> first slot row

__device__ __forceinline__ void gload_lds16(const f16* g, f16* l) {
  // global->LDS DMA, 16 B/lane. LDS dest is wave-uniform base + lane*16.
  __builtin_amdgcn_global_load_lds(
      (const __attribute__((address_space(1))) void*)g,
      (__attribute__((address_space(3))) void*)l, 16, 0, 0);
}

// ---------------- w1/w3 -> interleaved fp16 slice  [E][2*FS][D] -------------
__global__ __launch_bounds__(256) void cvt_w13_kernel(const float* __restrict__ w1,
                                                      const float* __restrict__ w3,
                                                      f16* __restrict__ w13,
                                                      int D, int F, int FS, int fbase) {
  long i = (long)blockIdx.x * 256 + threadIdx.x;          // float4 id
  long n4 = (long)NEXP * 2 * FS * (D / 4);
  if (i >= n4) return;
  int d4 = (int)(i % (D / 4));
  int rr = (int)((i / (D / 4)) % (2 * FS));
  int e  = (int)(i / ((long)(D / 4) * 2 * FS));
  const float* src = ((rr & 1) ? w3 : w1) + ((long)e * F + fbase + (rr >> 1)) * D + d4 * 4;
  float4 v = *(const float4*)src;
  f16x4 o = {(f16)v.x, (f16)v.y, (f16)v.z, (f16)v.w};
  *(f16x4*)(w13 + i * 4) = o;
}

// ---------------- w2 -> fp16 k-slice  [E][D][FS] ---------------------------
__global__ __launch_bounds__(256) void cvt_w2_kernel(const float* __restrict__ w2,
                                                     f16* __restrict__ w2s,
                                                     int D, int F, int FS, int fbase) {
  long i = (long)blockIdx.x * 256 + threadIdx.x;          // float4 id
  long n4 = (long)NEXP * D * (FS / 4);
  if (i >= n4) return;
  int k4 = (int)(i % (FS / 4));
  int d  = (int)((i / (FS / 4)) % D);
  int e  = (int)(i / ((long)(FS / 4) * D));
  const float* src = w2 + ((long)e * D + d) * F + fbase + k4 * 4;
  float4 v = *(const float4*)src;
  f16x4 o = {(f16)v.x, (f16)v.y, (f16)v.z, (f16)v.w};
  *(f16x4*)(w2s + i * 4) = o;
}

// ---------------- gating: fp32 logits, top-2, x->fp16 (no atomics) ---------
__global__ __launch_bounds__(256) void gate_kernel(const float* __restrict__ x,
                                                   const float* __restrict__ gw,
                                                   f16* __restrict__ xb,
                                                   int* __restrict__ topk_id,
                                                   float* __restrict__ topk_w,
                                                   int D) {
  const int lane = threadIdx.x & 63;
  const int wave = threadIdx.x >> 6;
  const long tok = (long)blockIdx.x * 4 + wave;
  const float* xrow = x + tok * D;

  float part[NEXP];
#pragma unroll
  for (int e = 0; e < NEXP; ++e) part[e] = 0.f;

  for (int c = 0; c < D / 256; ++c) {
    int idx = (c * 64 + lane) * 4;
    float4 xv = *(const float4*)(xrow + idx);
    f16x4 o = {(f16)xv.x, (f16)xv.y, (f16)xv.z, (f16)xv.w};
    *(f16x4*)(xb + tok * D + idx) = o;
#pragma unroll
    for (int e = 0; e < NEXP; ++e) {
      float4 gv = *(const float4*)(gw + (long)e * D + idx);
      part[e] += xv.x * gv.x + xv.y * gv.y + xv.z * gv.z + xv.w * gv.w;
    }
  }
#pragma unroll
  for (int e = 0; e < NEXP; ++e)
    for (int off = 32; off; off >>= 1) part[e] += __shfl_xor(part[e], off);

  // top-2, lowest index wins ties (matches lax.top_k stable ordering)
  int i0 = 0; float m0 = part[0];
#pragma unroll
  for (int e = 1; e < NEXP; ++e) if (part[e] > m0) { m0 = part[e]; i0 = e; }
  int i1 = (i0 == 0) ? 1 : 0; float m1 = part[i1];
#pragma unroll
  for (int e = 0; e < NEXP; ++e)
    if (e != i0 && e != ((i0 == 0) ? 1 : 0) && part[e] > m1) { m1 = part[e]; i1 = e; }

  if (lane == 0) {
    // renormalized top-2 softmax == sigmoid of logit difference (fp32 exact)
    float w0 = 1.f / (1.f + expf(m1 - m0));
    float w1 = 1.f / (1.f + expf(m0 - m1));
    topk_id[2 * tok] = i0; topk_id[2 * tok + 1] = i1;
    topk_w[2 * tok] = w0;  topk_w[2 * tok + 1] = w1;
  }
}

// ---------------- per-block expert histogram (LDS, no global contention) ----
__global__ __launch_bounds__(256) void count_kernel(const int* __restrict__ topk_id,
                                                    int* __restrict__ meta, int n2) {
  __shared__ int h[NEXP];
  const int t = threadIdx.x;
  if (t < NEXP) h[t] = 0;
  __syncthreads();
  const int lo = blockIdx.x * CHUNK;
  const int hi = min(n2, lo + CHUNK);
  for (int i = lo + t; i < hi; i += 256) atomicAdd(&h[topk_id[i]], 1);
  __syncthreads();
  if (t < NEXP) meta[M_PART + blockIdx.x * NEXP + t] = h[t];
}

// ---------------- offsets + tile map + per-block bases + pad fill ----------
__global__ void setup_kernel(int* __restrict__ meta, int* __restrict__ routed_token,
                             float* __restrict__ routed_w, int MT, int CB) {
  __shared__ int s_off[NEXP], s_cnt[NEXP];
  const int t = threadIdx.x;
  if (t == 0) {
    int cnt[NEXP];
    for (int e = 0; e < NEXP; ++e) cnt[e] = 0;
    for (int b = 0; b < CB; ++b)
      for (int e = 0; e < NEXP; ++e) cnt[e] += meta[M_PART + b * NEXP + e];
    int off = 0, tt = 0;
    for (int e = 0; e < NEXP; ++e) {
      s_cnt[e] = cnt[e]; s_off[e] = off;
      meta[M_OFF + e] = off;
      int p = (cnt[e] + 127) & ~127;
      for (int i = 0; i < (p >> 7); ++i) {
        meta[M_TE + tt] = e; meta[M_TR + tt] = off + i * 128; ++tt;
      }
      off += p;
    }
    meta[M_OFF + NEXP] = off;
    for (; tt < MT; ++tt) meta[M_TE + tt] = -1;
    // exclusive per-block scatter bases
    for (int e = 0; e < NEXP; ++e) {
      int run = meta[M_OFF + e];
      for (int b = 0; b < CB; ++b) {
        meta[M_BB + b * NEXP + e] = run;
        run += meta[M_PART + b * NEXP + e];
      }
    }
  }
  __syncthreads();
  for (int e = 0; e < NEXP; ++e) {
    int start = s_off[e] + s_cnt[e];
    int end = s_off[e] + ((s_cnt[e] + 127) & ~127);
    for (int i = start + t; i < end; i += blockDim.x) {
      routed_token[i] = 0;      // pad rows -> token 0 (finite garbage)
      routed_w[i] = 0.f;        // zero gate weight kills pad contribution
    }
  }
}

// ---------------- scatter tokens into per-expert slots (LDS cursors) -------
__global__ __launch_bounds__(256) void scatter_kernel(const int* __restrict__ topk_id,
                                                      const float* __restrict__ topk_w,
                                                      const int* __restrict__ meta,
                                                      int* __restrict__ routed_token,
                                                      float* __restrict__ routed_w,
                                                      int n2) {
  __shared__ int cur[NEXP];
  const int t = threadIdx.x;
  if (t < NEXP) cur[t] = meta[M_BB + blockIdx.x * NEXP + t];
  __syncthreads();
  const int lo = blockIdx.x * CHUNK;
  const int hi = min(n2, lo + CHUNK);
  for (int i = lo + t; i < hi; i += 256) {
    int e = topk_id[i];
    int pos = atomicAdd(&cur[e], 1);
    routed_token[pos] = i >> 1;
    routed_w[pos] = topk_w[i];
  }
}

// ---------------- GEMM1: h = gate_w * silu(X w1^T) * (X w3^T) --------------
// Tile: 128 token-rows x 128 interleaved weight-rows (2j=w1[f0+j], 2j+1=w3).
// Waves 2x2 (64x64 each). BK=64, 2 MFMA K-steps per chunk.
__global__ __launch_bounds__(256) void ffn1_kernel(const f16* __restrict__ xb,
                                                   const f16* __restrict__ w13,
                                                   const int* __restrict__ routed_token,
                                                   const float* __restrict__ routed_w,
                                                   const int* __restrict__ meta,
                                                   f16* __restrict__ hbuf,
                                                   int D, int FS) {
  const int e = meta[M_TE + blockIdx.x];
  if (e < 0) return;
  const int r0 = meta[M_TR + blockIdx.x];
  const int f0 = blockIdx.y * 64;          // local to this F-slice

  __shared__ __align__(16) f16 smem[2 * 128 * 64];  // 32 KiB: sA | sB; epilogue reuses
  __shared__ float s_w[128];
  f16* sA = smem;
  f16* sB = smem + 128 * 64;

  const int t = threadIdx.x;
  const int lane = t & 63;
  const int wave = t >> 6;
  const int wm = (wave & 1) * 64;
  const int wn = (wave >> 1) * 64;

  if (t < 128) s_w[t] = routed_w[r0 + t];

  // staging: thread t owns granule gi=q*256+t -> row q*32+(t>>3), col-gran t&7.
  // XOR swizzle on the GLOBAL side: LDS (r,g) holds global (r, g^(r&7)).
  const int rb = t >> 3;
  const int sgg = (t & 7) ^ (rb & 7);
  const f16* aptr[4];
  const f16* bptr[4];
#pragma unroll
  for (int q = 0; q < 4; ++q) {
    int r = q * 32 + rb;
    int tok = routed_token[r0 + r];
    aptr[q] = xb + (long)tok * D + sgg * 8;
    bptr[q] = w13 + ((long)e * 2 * FS + 2 * f0 + r) * D + sgg * 8;
  }
  f16* ldsA[4]; f16* ldsB[4];
#pragma unroll
  for (int q = 0; q < 4; ++q) {
    int gbase = (q * 256 + (t & ~63)) * 8;   // wave-uniform
    ldsA[q] = sA + gbase;
    ldsB[q] = sB + gbase;
  }

  fx4 acc[4][4];
#pragma unroll
  for (int i = 0; i < 4; ++i)
#pragma unroll
    for (int j = 0; j < 4; ++j) acc[i][j] = (fx4){0.f, 0.f, 0.f, 0.f};

  for (int kc = 0; kc < D; kc += 64) {
#pragma unroll
    for (int q = 0; q < 4; ++q) {
      gload_lds16(aptr[q] + kc, ldsA[q]);
      gload_lds16(bptr[q] + kc, ldsB[q]);
    }
    __syncthreads();
#pragma unroll
    for (int ks = 0; ks < 2; ++ks) {
      f16x8 aF[4], bF[4];
      const int kg = ks * 4 + (lane >> 4);
#pragma unroll
      for (int mf = 0; mf < 4; ++mf) {
        int row = wm + mf * 16 + (lane & 15);
        aF[mf] = *(const f16x8*)(sA + row * 64 + (kg ^ (row & 7)) * 8);
      }
#pragma unroll
      for (int nf = 0; nf < 4; ++nf) {
        int row = wn + nf * 16 + (lane & 15);
        bF[nf] = *(const f16x8*)(sB + row * 64 + (kg ^ (row & 7)) * 8);
      }
#pragma unroll
      for (int mf = 0; mf < 4; ++mf)
#pragma unroll
        for (int nf = 0; nf < 4; ++nf)
          acc[mf][nf] = __builtin_amdgcn_mfma_f32_16x16x32_f16(aF[mf], bF[nf], acc[mf][nf], 0, 0, 0);
    }
    __syncthreads();
  }

  // epilogue: dedup even(w1)/odd(w3) pairing across nf-pairs so each lane
  // computes 32 UNIQUE silu values (native v_exp/v_rcp), scaled by gate w.
  f16* sH = smem;                       // [128][72] padded (+8 kills write conflicts)
  const int odd = lane & 1;
  const int j = (lane & 15) >> 1;
#pragma unroll
  for (int mf = 0; mf < 4; ++mf)
#pragma unroll
    for (int nfp = 0; nfp < 4; nfp += 2)
#pragma unroll
      for (int rg = 0; rg < 4; ++rg) {
        float v0 = acc[mf][nfp][rg];
        float v1 = acc[mf][nfp + 1][rg];
        float t0 = __shfl_xor(v0, 1);   // even lane: c3 of (nfp,   j)
        float t1 = __shfl_xor(v1, 1);   // odd  lane: c1 of (nfp+1, j)
        float c1 = odd ? t1 : v0;
        float c3 = odd ? v1 : t0;
        float ex = __expf(-c1);
        float hv = c1 * c3 * __builtin_amdgcn_rcpf(1.f + ex);
        int ml = wm + mf * 16 + (lane >> 4) * 4 + rg;
        int fl = (wn >> 1) + (nfp + odd) * 8 + j;
        sH[ml * 72 + fl] = (f16)(hv * s_w[ml]);
      }
  __syncthreads();
#pragma unroll
  for (int q = 0; q < 4; ++q) {
    int gi = q * 256 + t;
    int r = gi >> 3, gc = gi & 7;
    *(f16x8*)(hbuf + (long)(r0 + r) * FS + f0 + gc * 8) = *(const f16x8*)(sH + r * 72 + gc * 8);
  }
}

// ---------------- GEMM2: out[tok] += (h @ w2^T) slice (h pre-weighted) -----
__global__ __launch_bounds__(256) void ffn2_kernel(const f16* __restrict__ hbuf,
                                                   const f16* __restrict__ w2s,
                                                   const int* __restrict__ routed_token,
                                                   const int* __restrict__ meta,
                                                   float* __restrict__ out,
                                                   int D, int FS) {
  const int e = meta[M_TE + blockIdx.x];
  if (e < 0) return;
  const int r0 = meta[M_TR + blockIdx.x];
  const int d0 = blockIdx.y * 128;

  __shared__ __align__(16) f16 smem[2 * 128 * 64];   // 32 KiB staging
  __shared__ int s_tok[128];
  f16* sA = smem;
  f16* sB = smem + 128 * 64;

  const int t = threadIdx.x;
  const int lane = t & 63;
  const int wave = t >> 6;
  const int wm = (wave & 1) * 64;
  const int wn = (wave >> 1) * 64;

  if (t < 128) s_tok[t] = routed_token[r0 + t];

  const int rb = t >> 3;
  const int sgg = (t & 7) ^ (rb & 7);
  const f16* aptr[4];
  const f16* bptr[4];
#pragma unroll
  for (int q = 0; q < 4; ++q) {
    int r = q * 32 + rb;
    aptr[q] = hbuf + (long)(r0 + r) * FS + sgg * 8;
    bptr[q] = w2s + ((long)e * D + d0 + r) * FS + sgg * 8;
  }
  f16* ldsA[4]; f16* ldsB[4];
#pragma unroll
  for (int q = 0; q < 4; ++q) {
    int gbase = (q * 256 + (t & ~63)) * 8;
    ldsA[q] = sA + gbase;
    ldsB[q] = sB + gbase;
  }

  fx4 acc[4][4];
#pragma unroll
  for (int i = 0; i < 4; ++i)
#pragma unroll
    for (int j = 0; j < 4; ++j) acc[i][j] = (fx4){0.f, 0.f, 0.f, 0.f};

  for (int kc = 0; kc < FS; kc += 64) {
#pragma unroll
    for (int q = 0; q < 4; ++q) {
      gload_lds16(aptr[q] + kc, ldsA[q]);
      gload_lds16(bptr[q] + kc, ldsB[q]);
    }
    __syncthreads();
#pragma unroll
    for (int ks = 0; ks < 2; ++ks) {
      f16x8 aF[4], bF[4];
      const int kg = ks * 4 + (lane >> 4);
#pragma unroll
      for (int mf = 0; mf < 4; ++mf) {
        int row = wm + mf * 16 + (lane & 15);
        aF[mf] = *(const f16x8*)(sA + row * 64 + (kg ^ (row & 7)) * 8);
      }
#pragma unroll
      for (int nf = 0; nf < 4; ++nf) {
        int row = wn + nf * 16 + (lane & 15);
        bF[nf] = *(const f16x8*)(sB + row * 64 + (kg ^ (row & 7)) * 8);
      }
#pragma unroll
      for (int mf = 0; mf < 4; ++mf)
#pragma unroll
        for (int nf = 0; nf < 4; ++nf)
          acc[mf][nf] = __builtin_amdgcn_mfma_f32_16x16x32_f16(aF[mf], bF[nf], acc[mf][nf], 0, 0, 0);
    }
    __syncthreads();
  }

  // epilogue: out[tok, d0+nl] += acc  (h was pre-weighted; pads add 0.0)
#pragma unroll
  for (int mf = 0; mf < 4; ++mf) {
#pragma unroll
    for (int rg = 0; rg < 4; ++rg) {
      int row = wm + mf * 16 + (lane >> 4) * 4 + rg;
      long obase = (long)s_tok[row] * D + d0;
#pragma unroll
      for (int nf = 0; nf < 4; ++nf) {
        int nl = wn + nf * 16 + (lane & 15);
        atomicAdd(out + obase + nl, acc[mf][nf][rg]);
      }
    }
  }
}

// ---------------------------------------------------------------------------
extern "C" void kernel_launch(void* const* d_in, const int* in_sizes, int n_in,
                              void* d_out, int out_size, void* d_ws, size_t ws_size,
                              hipStream_t stream) {
  const float* x  = (const float*)d_in[0];
  const float* gw = (const float*)d_in[1];
  const float* w1 = (const float*)d_in[2];
  const float* w2 = (const float*)d_in[3];
  const float* w3 = (const float*)d_in[4];
  float* out = (float*)d_out;

  const int E = NEXP;
  const int D = in_sizes[1] / E;                              // 1024
  const long N = (long)in_sizes[0] / D;                       // 16384
  const int F = (int)((long)in_sizes[2] / ((long)E * D));     // 2048
  const int MT = (int)(2 * N / 128 + E);                      // 264 m-tiles max
  const long RMAX = (long)MT * 128;
  const long out_bytes = (long)out_size * 4;
  const int n2 = (int)(2 * N);
  const int CB = (n2 + CHUNK - 1) / CHUNK;                    // 32 routing blocks

  char* base = (char*)d_ws;
  long off = 0;
  int*   meta         = (int*)(base + off); off += 8 * 1024;
  int*   topk_id      = (int*)(base + off); off += 2 * N * 4;
  float* topk_w       = (float*)(base + off); off += 2 * N * 4;
  int*   routed_token = (int*)(base + off); off += RMAX * 4;
  float* routed_w     = (float*)(base + off); off += RMAX * 4;
  off = (off + 255) & ~255L;
  f16* xb = (f16*)(base + off); off += N * (long)D * 2;
  const long fixed = off;

  // choose slicing S so everything fits. Fast path: w13 lives in d_out (64MB).
  int S = 0; bool w13_in_dout = false;
  {
    long need1 = fixed + (long)E * D * F * 2 + RMAX * (long)F * 2;
    if (need1 <= (long)ws_size && out_bytes >= (long)E * 2 * F * D * 2) {
      S = 1; w13_in_dout = true;
    } else {
      const int cands[4] = {2, 4, 8, 16};
      for (int ci = 0; ci < 4 && !S; ++ci) {
        int s = cands[ci];
        if (F % (64 * s)) continue;
        long FSl = F / s;
        long need = fixed + (long)E * D * FSl * 2 + RMAX * FSl * 2 + (long)E * 2 * FSl * D * 2;
        if (need <= (long)ws_size) S = s;
      }
    }
  }
  if (!S) return;
  const int FS = F / S;
  f16* w2s = (f16*)(base + off); off += (long)E * D * FS * 2;
  f16* hbuf = (f16*)(base + off); off += RMAX * (long)FS * 2;
  f16* w13 = w13_in_dout ? (f16*)d_out : (f16*)(base + off);

  hipMemsetAsync(meta, 0, 8 * 1024, stream);
  gate_kernel<<<(int)(N / 4), 256, 0, stream>>>(x, gw, xb, topk_id, topk_w, D);
  count_kernel<<<CB, 256, 0, stream>>>(topk_id, meta, n2);
  setup_kernel<<<1, 256, 0, stream>>>(meta, routed_token, routed_w, MT, CB);
  scatter_kernel<<<CB, 256, 0, stream>>>(topk_id, topk_w, meta, routed_token, routed_w, n2);

  const long n13 = (long)E * 2 * FS * (D / 4);
  const long nw2 = (long)E * D * (FS / 4);
  const int b13 = (int)((n13 + 255) / 256);
  const int bw2 = (int)((nw2 + 255) / 256);

  if (w13_in_dout) {
    cvt_w13_kernel<<<b13, 256, 0, stream>>>(w1, w3, w13, D, F, FS, 0);
    cvt_w2_kernel<<<bw2, 256, 0, stream>>>(w2, w2s, D, F, FS, 0);
    dim3 g1(MT, FS / 64);
    ffn1_kernel<<<g1, 256, 0, stream>>>(xb, w13, routed_token, routed_w, meta, hbuf, D, FS);
    hipMemsetAsync(out, 0, out_bytes, stream);   // w13 (in d_out) dead now
    dim3 g2(MT, D / 128);
    ffn2_kernel<<<g2, 256, 0, stream>>>(hbuf, w2s, routed_token, meta, out, D, FS);
  } else {
    hipMemsetAsync(out, 0, out_bytes, stream);
    for (int s = 0; s < S; ++s) {
      int fbase = s * FS;
      cvt_w13_kernel<<<b13, 256, 0, stream>>>(w1, w3, w13, D, F, FS, fbase);
      cvt_w2_kernel<<<bw2, 256, 0, stream>>>(w2, w2s, D, F, FS, fbase);
      dim3 g1(MT, FS / 64);
      ffn1_kernel<<<g1, 256, 0, stream>>>(xb, w13, routed_token, routed_w, meta, hbuf, D, FS);
      dim3 g2(MT, D / 128);
      ffn2_kernel<<<g2, 256, 0, stream>>>(hbuf, w2s, routed_token, meta, out, D, FS);
    }
  }
}